// Round 4
// baseline (1325.922 us; speedup 1.0000x reference)
//
#include <hip/hip_runtime.h>
#include <hip/hip_bf16.h>

#define BB 64
#define SS 2048
#define DD 512
#define UU 512
#define BS (BB*SS)   // 131072

typedef __attribute__((ext_vector_type(8))) short bf16x8;
typedef __attribute__((ext_vector_type(16))) float f32x16;

static __device__ __forceinline__ unsigned short f2bf(float x) {
    union { float f; unsigned int u; } v; v.f = x;
    unsigned int r = v.u + 0x7FFFu + ((v.u >> 16) & 1u);
    return (unsigned short)(r >> 16);
}

// ---- prep: blocks 0..63 pack W2 -> W2F (MFMA B-fragment-major, bf16);
//            blocks 64..127 qproj ----
// W2F granule index: ((ks*16 + ntile)*64 + lane), 8 bf16 each.
//   n = ntile*32 + (lane&31), k = ks*16 + (lane>>5)*8 + j
__global__ void k_prep(const float* __restrict__ W2, unsigned short* __restrict__ W2F,
                       const float* __restrict__ query, const float* __restrict__ W1,
                       const float* __restrict__ b1, const float* __restrict__ b2,
                       float* __restrict__ qpb) {
    __shared__ float tile[64][65];
    const int t = threadIdx.x;
    if (blockIdx.x < 64) {
        const int ti = blockIdx.x >> 3;   // d-tile (k)
        const int tj = blockIdx.x & 7;    // u-tile (n)
        #pragma unroll
        for (int i = 0; i < 16; ++i) {
            int e = i*256 + t;
            int dr = e >> 6, uc = e & 63;
            tile[dr][uc] = W2[(size_t)(ti*64+dr)*UU + tj*64+uc];
        }
        __syncthreads();
        const int ksl = t >> 6, ln = t & 63;
        const int lh = ln >> 5, l31 = ln & 31;
        #pragma unroll
        for (int ntl = 0; ntl < 2; ++ntl) {
            const int ks = ti*4 + ksl;
            const int ntile = tj*2 + ntl;
            bf16x8 g;
            #pragma unroll
            for (int j = 0; j < 8; ++j)
                g[j] = (short)f2bf(tile[ksl*16 + lh*8 + j][ntl*32 + l31]);
            *(bf16x8*)&W2F[(size_t)(((ks*16 + ntile)*64 + ln) * 8)] = g;
        }
    } else {
        const int b = blockIdx.x - 64;
        float a0 = 0.f, a1 = 0.f, a2 = 0.f, a3 = 0.f;
        for (int d = 0; d < DD; d += 2) {
            float q0 = query[b*DD + d], q1 = query[b*DD + d + 1];
            a0 = fmaf(q0, W1[(size_t)d*UU + t], a0);
            a1 = fmaf(q1, W1[(size_t)(d+1)*UU + t], a1);
            a2 = fmaf(q0, W1[(size_t)d*UU + t + 256], a2);
            a3 = fmaf(q1, W1[(size_t)(d+1)*UU + t + 256], a3);
        }
        qpb[b*UU + t]       = a0 + a1 + b1[t]     + b2[t];
        qpb[b*UU + t + 256] = a2 + a3 + b1[t+256] + b2[t+256];
    }
}

// ---- fused scores + per-block softmax stats + fp32 partial context ----
// 64 rows/block as TWO sequential 32-row tiles (32 KB LDS -> 5 blocks/CU).
// N=512 (4 waves x 128 cols), K=512, 32x32x16 MFMA, B prefetch distance 4.
__launch_bounds__(256, 5)
__global__ void k_scores(const float* __restrict__ values,
                         const unsigned short* __restrict__ W2F,
                         const float* __restrict__ qpb,
                         const float* __restrict__ Vw,
                         float* __restrict__ pm, float* __restrict__ pl,
                         float* __restrict__ pv) {
    __shared__ unsigned short Albuf[32*512];   // 32 KB: one 32-row tile, full K
    const int t   = threadIdx.x;
    const int blk = blockIdx.x;
    const int m0  = blk * 64;
    const int b   = blk >> 5;                  // 32 blocks per batch
    const int wave = t >> 6, lane = t & 63;
    const int ln31 = lane & 31, half = lane >> 5;
    const int xm = ln31 & 7;

    // epilogue constants
    float qv[4], vw[4];
    #pragma unroll
    for (int nt = 0; nt < 4; ++nt) {
        int n = wave*128 + nt*32 + ln31;
        qv[nt] = qpb[b*UU + n];
        vw[nt] = Vw[n];
    }

    const bf16x8* Bp = (const bf16x8*)W2F;
    float sacc[2][16];
    #pragma unroll
    for (int tau = 0; tau < 2; ++tau)
        #pragma unroll
        for (int r = 0; r < 16; ++r)
            sacc[tau][r] = 0.f;

    for (int tau = 0; tau < 2; ++tau) {
        // --- stage A tile: 32 rows fp32 -> bf16, XOR-swizzled 16B granules ---
        const float* src = values + (size_t)(m0 + tau*32) * DD;
        #pragma unroll
        for (int i = 0; i < 8; ++i) {
            int gf  = i*256 + t;               // 2048 granules (8 floats each)
            int row = gf >> 6;                 // 0..31
            int g   = gf & 63;
            const float4 f0 = *(const float4*)(src + (size_t)row*DD + g*8);
            const float4 f1 = *(const float4*)(src + (size_t)row*DD + g*8 + 4);
            bf16x8 pk;
            pk[0] = (short)f2bf(f0.x); pk[1] = (short)f2bf(f0.y);
            pk[2] = (short)f2bf(f0.z); pk[3] = (short)f2bf(f0.w);
            pk[4] = (short)f2bf(f1.x); pk[5] = (short)f2bf(f1.y);
            pk[6] = (short)f2bf(f1.z); pk[7] = (short)f2bf(f1.w);
            *(bf16x8*)&Albuf[row*512 + ((g ^ (row & 7)) << 3)] = pk;
        }

        // B prologue: ksteps 0..3 (distance-4 pipeline), coalesced frag loads
        bf16x8 bfr[4][4];
        #pragma unroll
        for (int p = 0; p < 4; ++p)
            #pragma unroll
            for (int nt = 0; nt < 4; ++nt)
                bfr[p][nt] = Bp[(p*16 + wave*4 + nt)*64 + lane];

        __syncthreads();

        // --- K-loop: 32 ksteps, 4 MFMA each, no barriers ---
        f32x16 acc[4];
        #pragma unroll
        for (int nt = 0; nt < 4; ++nt)
            #pragma unroll
            for (int r = 0; r < 16; ++r)
                acc[nt][r] = 0.f;

        #pragma unroll 4
        for (int ks = 0; ks < 32; ++ks) {
            const int slot = ks & 3;
            bf16x8 a0 = *(const bf16x8*)&Albuf[ln31*512 + (((ks*2 + half) ^ xm) << 3)];
            #pragma unroll
            for (int nt = 0; nt < 4; ++nt)
                acc[nt] = __builtin_amdgcn_mfma_f32_32x32x16_bf16(a0, bfr[slot][nt], acc[nt], 0, 0, 0);
            // prefetch ks+4 (W2F padded by 4 ksteps -> branchless; pad never MFMA'd)
            #pragma unroll
            for (int nt = 0; nt < 4; ++nt)
                bfr[slot][nt] = Bp[((ks+4)*16 + wave*4 + nt)*64 + lane];
        }

        // epilogue math (regs only): h = tanh(qv + vproj); sacc += h * vw
        #pragma unroll
        for (int nt = 0; nt < 4; ++nt) {
            const float q = qv[nt], w = vw[nt];
            #pragma unroll
            for (int r = 0; r < 16; ++r) {
                float x = q + acc[nt][r];
                float e = __expf(x + x);
                float rc = __builtin_amdgcn_rcpf(e + 1.f);
                sacc[tau][r] = fmaf(fmaf(-2.f, rc, 1.f), w, sacc[tau][r]);
            }
        }
        __syncthreads();   // all waves done with Albuf before restage/reuse
    }

    // --- reduction: 32 lanes (cols) per value, then cross-wave via LDS ---
    float* sred = (float*)Albuf;               // [4 waves][64 rows] + p[64]
    #pragma unroll
    for (int tau = 0; tau < 2; ++tau)
        #pragma unroll
        for (int r = 0; r < 16; ++r) {
            float v = sacc[tau][r];
            v += __shfl_xor(v, 1);
            v += __shfl_xor(v, 2);
            v += __shfl_xor(v, 4);
            v += __shfl_xor(v, 8);
            v += __shfl_xor(v, 16);
            if (ln31 == 0)
                sred[wave*64 + tau*32 + (r & 3) + 8*(r >> 2) + 4*half] = v;
        }
    __syncthreads();

    // block softmax stats over its 64 rows
    if (t < 64) {
        float s = sred[t] + sred[64 + t] + sred[128 + t] + sred[192 + t];
        float m = s;
        #pragma unroll
        for (int off = 32; off; off >>= 1) m = fmaxf(m, __shfl_xor(m, off));
        float p = __expf(s - m);
        float l = p;
        #pragma unroll
        for (int off = 32; off; off >>= 1) l += __shfl_xor(l, off);
        sred[256 + t] = p;
        if (t == 0) { pm[blk] = m; pl[blk] = l; }
    }
    __syncthreads();

    // partial context over 64 rows (values re-read, L2/L3-hot, coalesced)
    float2 cacc = make_float2(0.f, 0.f);
    const float* vrow = values + (size_t)m0*DD + t*2;
    #pragma unroll 8
    for (int i = 0; i < 64; ++i) {
        float p = sred[256 + i];
        float2 v = *(const float2*)(vrow + (size_t)i*DD);
        cacc.x = fmaf(p, v.x, cacc.x);
        cacc.y = fmaf(p, v.y, cacc.y);
    }
    *(float2*)&pv[(size_t)blk*DD + t*2] = cacc;
}

// ---- finish: combine 32 chunks per batch with online-softmax rescale ----
__global__ void k_finish(const float* __restrict__ pv, const float* __restrict__ pm,
                         const float* __restrict__ pl, float* __restrict__ out) {
    __shared__ float sw[32];
    const int b = blockIdx.x >> 2, d0 = (blockIdx.x & 3) * 128;
    const int t = threadIdx.x;
    if (t < 32) {
        float m = pm[b*32 + t], l = pl[b*32 + t];
        float M = m;
        #pragma unroll
        for (int off = 16; off; off >>= 1) M = fmaxf(M, __shfl_xor(M, off));
        float le = l * __expf(m - M);
        float L = le;
        #pragma unroll
        for (int off = 16; off; off >>= 1) L += __shfl_xor(L, off);
        sw[t] = __expf(m - M) / L;
    }
    __syncthreads();
    if (t < 128) {
        float a = 0.f;
        #pragma unroll 4
        for (int c = 0; c < 32; ++c)
            a = fmaf(sw[c], pv[(size_t)(b*32 + c)*DD + d0 + t], a);
        out[(size_t)b*DD + d0 + t] = a;
    }
}

extern "C" void kernel_launch(void* const* d_in, const int* in_sizes, int n_in,
                              void* d_out, int out_size, void* d_ws, size_t ws_size,
                              hipStream_t stream) {
    const float* query  = (const float*)d_in[0];
    const float* values = (const float*)d_in[1];
    const float* W1     = (const float*)d_in[2];
    const float* b1     = (const float*)d_in[3];
    const float* W2     = (const float*)d_in[4];
    const float* b2     = (const float*)d_in[5];
    const float* Vw     = (const float*)d_in[6];
    // d_in[7] = bv: softmax over s is shift-invariant -> no-op

    char* ws = (char*)d_ws;
    unsigned short* W2F = (unsigned short*)ws;            // 512 KB + 64 KB pad = 576 KB
    float* qpb = (float*)(ws + 589824);                   // 128 KB
    float* pm  = (float*)(ws + 589824 + 131072);          // 8 KB
    float* pl  = (float*)(ws + 589824 + 131072 + 8192);   // 8 KB
    float* pv  = (float*)(ws + 589824 + 131072 + 16384);  // 4 MB

    k_prep<<<128, 256, 0, stream>>>(W2, W2F, query, W1, b1, b2, qpb);
    k_scores<<<BS/64, 256, 0, stream>>>(values, W2F, qpb, Vw, pm, pl, pv);
    k_finish<<<BB*4, 256, 0, stream>>>(pv, pm, pl, (float*)d_out);
}